// Round 1
// baseline (4304.472 us; speedup 1.0000x reference)
//
#include <hip/hip_runtime.h>
#include <math.h>

#define NN 50000
#define NE 800000
#define DD 64
#define N_GCN 30
#define N_GGC 8
#define NB ((NN + 255) / 256)

__device__ __forceinline__ float lane_bcast(float v, int k) {
    return __int_as_float(__builtin_amdgcn_readlane(__float_as_int(v), k));
}

// ---------------- graph prep ----------------

__global__ void hist_kernel(const int* __restrict__ dst, int* __restrict__ cnt) {
    int i = blockIdx.x * blockDim.x + threadIdx.x;
    if (i < NE) atomicAdd(&cnt[dst[i]], 1);
}

__global__ void dinv_kernel(const int* __restrict__ cnt, float* __restrict__ dinv) {
    int i = blockIdx.x * blockDim.x + threadIdx.x;
    if (i < NN) dinv[i] = rsqrtf((float)cnt[i] + 1.0f);
}

__global__ void scan1_kernel(const int* __restrict__ cnt, int* __restrict__ bsum) {
    __shared__ int s[256];
    int tid = threadIdx.x;
    int i = blockIdx.x * 256 + tid;
    s[tid] = (i < NN) ? cnt[i] : 0;
    __syncthreads();
    for (int off = 128; off > 0; off >>= 1) {
        if (tid < off) s[tid] += s[tid + off];
        __syncthreads();
    }
    if (tid == 0) bsum[blockIdx.x] = s[0];
}

__global__ void scan2_kernel(int* __restrict__ bsum) {
    if (threadIdx.x == 0 && blockIdx.x == 0) {
        int acc = 0;
        for (int b = 0; b < NB; b++) { int v = bsum[b]; bsum[b] = acc; acc += v; }
        bsum[NB] = acc;
    }
}

__global__ void scan3_kernel(const int* __restrict__ cnt, const int* __restrict__ bsum,
                             int* __restrict__ rowptr) {
    __shared__ int s[256];
    int tid = threadIdx.x;
    int i = blockIdx.x * 256 + tid;
    int v = (i < NN) ? cnt[i] : 0;
    s[tid] = v;
    __syncthreads();
    for (int off = 1; off < 256; off <<= 1) {
        int t = (tid >= off) ? s[tid - off] : 0;
        __syncthreads();
        s[tid] += t;
        __syncthreads();
    }
    if (i < NN) rowptr[i] = bsum[blockIdx.x] + s[tid] - v;
    if (i == NN - 1) rowptr[NN] = bsum[blockIdx.x] + s[tid];
}

__global__ void fill_kernel(const int* __restrict__ src, const int* __restrict__ dst,
                            const float* __restrict__ dinv, const int* __restrict__ rowptr,
                            int* __restrict__ cur, int* __restrict__ csrc, float* __restrict__ cw) {
    int i = blockIdx.x * blockDim.x + threadIdx.x;
    if (i >= NE) return;
    int s = src[i], d = dst[i];
    int pos = atomicAdd(&cur[d], 1);
    int idx = rowptr[d] + pos;
    csrc[idx] = s;
    cw[idx] = dinv[s] * dinv[d];
}

// ---------------- weight prep (transposes) ----------------

__global__ void prep_weights(const float* __restrict__ lw, const float* __restrict__ gw,
                             const float* __restrict__ wih, const float* __restrict__ whh,
                             float* __restrict__ lin_wt, float* __restrict__ gcn_wt,
                             float* __restrict__ wih_t, float* __restrict__ whh_t) {
    int i = blockIdx.x * blockDim.x + threadIdx.x;
    if (i < 8192) {              // lin_wt[k*64+j] = lw[j*128+k], k<128, j<64
        int k = i >> 6, j = i & 63;
        lin_wt[k * 64 + j] = lw[j * 128 + k];
    }
    if (i < 122880) {            // gcn_wt[l][k][j] = gw[l][j][k]
        int l = i >> 12, r = i & 4095;
        int k = r >> 6, j = r & 63;
        gcn_wt[l * 4096 + k * 64 + j] = gw[l * 4096 + j * 64 + k];
    }
    if (i < 12288) {             // i = j*64+k, j<192, k<64
        int j = i >> 6, k = i & 63;
        wih_t[k * 192 + j] = wih[i];
        whh_t[k * 192 + j] = whh[i];
    }
}

// ---------------- init linear: h = relu(x @ lw^T + lb), K=128 ----------------

__global__ __launch_bounds__(256) void init_linear(const float* __restrict__ x,
                                                   const float* __restrict__ lin_wt,
                                                   const float* __restrict__ lb,
                                                   float* __restrict__ h) {
    int lane = threadIdx.x & 63;
    int wv = blockIdx.x * (blockDim.x >> 6) + (threadIdx.x >> 6);
    int nw = gridDim.x * (blockDim.x >> 6);
    float w[128];
#pragma unroll
    for (int k = 0; k < 128; k++) w[k] = lin_wt[k * 64 + lane];
    float b = lb[lane];
    for (int n = wv; n < NN; n += nw) {
        float x0 = x[n * 128 + lane];
        float x1 = x[n * 128 + 64 + lane];
        float a0 = b, a1 = 0.f, a2 = 0.f, a3 = 0.f;
#pragma unroll
        for (int k = 0; k < 64; k += 4) {
            a0 = fmaf(lane_bcast(x0, k), w[k], a0);
            a1 = fmaf(lane_bcast(x0, k + 1), w[k + 1], a1);
            a2 = fmaf(lane_bcast(x0, k + 2), w[k + 2], a2);
            a3 = fmaf(lane_bcast(x0, k + 3), w[k + 3], a3);
        }
#pragma unroll
        for (int k = 0; k < 64; k += 4) {
            a0 = fmaf(lane_bcast(x1, k), w[64 + k], a0);
            a1 = fmaf(lane_bcast(x1, k + 1), w[64 + k + 1], a1);
            a2 = fmaf(lane_bcast(x1, k + 2), w[64 + k + 2], a2);
            a3 = fmaf(lane_bcast(x1, k + 3), w[64 + k + 3], a3);
        }
        h[n * 64 + lane] = fmaxf((a0 + a1) + (a2 + a3), 0.0f);
    }
}

// ---------------- mm64: out[n][j] = sum_k in[n][k] * wt[k][j] ----------------

__global__ __launch_bounds__(256) void mm64_kernel(const float* __restrict__ in,
                                                   const float* __restrict__ wt,
                                                   float* __restrict__ out) {
    int lane = threadIdx.x & 63;
    int wv = blockIdx.x * (blockDim.x >> 6) + (threadIdx.x >> 6);
    int nw = gridDim.x * (blockDim.x >> 6);
    float w[64];
#pragma unroll
    for (int k = 0; k < 64; k++) w[k] = wt[k * 64 + lane];
    for (int n = wv; n < NN; n += nw) {
        float hreg = in[n * 64 + lane];
        float a0 = 0.f, a1 = 0.f, a2 = 0.f, a3 = 0.f;
#pragma unroll
        for (int k = 0; k < 64; k += 4) {
            a0 = fmaf(lane_bcast(hreg, k), w[k], a0);
            a1 = fmaf(lane_bcast(hreg, k + 1), w[k + 1], a1);
            a2 = fmaf(lane_bcast(hreg, k + 2), w[k + 2], a2);
            a3 = fmaf(lane_bcast(hreg, k + 3), w[k + 3], a3);
        }
        out[n * 64 + lane] = (a0 + a1) + (a2 + a3);
    }
}

// ---------------- mm192: out[n][g*64+j] = bias + sum_k in[n][k] * wt[k][g*64+j] ----

__global__ __launch_bounds__(256, 2) void mm192_kernel(const float* __restrict__ in,
                                                       const float* __restrict__ wt,
                                                       const float* __restrict__ bias,
                                                       float* __restrict__ out) {
    int lane = threadIdx.x & 63;
    int wv = blockIdx.x * (blockDim.x >> 6) + (threadIdx.x >> 6);
    int nw = gridDim.x * (blockDim.x >> 6);
    float w[192];
#pragma unroll
    for (int k = 0; k < 64; k++) {
        w[k * 3 + 0] = wt[k * 192 + lane];
        w[k * 3 + 1] = wt[k * 192 + 64 + lane];
        w[k * 3 + 2] = wt[k * 192 + 128 + lane];
    }
    float b0 = bias[lane], b1 = bias[64 + lane], b2 = bias[128 + lane];
    for (int n = wv; n < NN; n += nw) {
        float hreg = in[n * 64 + lane];
        float a0 = b0, a1 = b1, a2 = b2;
#pragma unroll
        for (int k = 0; k < 64; k++) {
            float hv = lane_bcast(hreg, k);
            a0 = fmaf(hv, w[k * 3 + 0], a0);
            a1 = fmaf(hv, w[k * 3 + 1], a1);
            a2 = fmaf(hv, w[k * 3 + 2], a2);
        }
        out[n * 192 + lane] = a0;
        out[n * 192 + 64 + lane] = a1;
        out[n * 192 + 128 + lane] = a2;
    }
}

// ---------------- aggregation: wave per node over CSR ----------------

template <bool NORM>
__global__ __launch_bounds__(256) void agg_kernel(const float* __restrict__ xw,
                                                  const int* __restrict__ rowptr,
                                                  const int* __restrict__ csrc,
                                                  const float* __restrict__ cw,
                                                  const float* __restrict__ dinv,
                                                  const float* __restrict__ bias,
                                                  float* __restrict__ out) {
    int lane = threadIdx.x & 63;
    int wv = blockIdx.x * (blockDim.x >> 6) + (threadIdx.x >> 6);
    int nw = gridDim.x * (blockDim.x >> 6);
    for (int n = wv; n < NN; n += nw) {
        float acc;
        if (NORM) {
            float di = dinv[n];
            acc = bias[lane] + di * di * xw[n * 64 + lane];
        } else {
            acc = 0.0f;
        }
        int e0 = rowptr[n], e1 = rowptr[n + 1];
        for (int e = e0; e < e1; e++) {
            int s = csrc[e];
            float wgt = NORM ? cw[e] : 1.0f;
            acc = fmaf(wgt, xw[s * 64 + lane], acc);
        }
        out[n * 64 + lane] = acc;
    }
}

// ---------------- fused GRU: h' = (1-z)*n + z*h ----------------

__global__ __launch_bounds__(256, 2) void gru_kernel(const float* __restrict__ hin,
                                                     const float* __restrict__ gi,
                                                     const float* __restrict__ whh_t,
                                                     const float* __restrict__ bhh,
                                                     float* __restrict__ hout) {
    int lane = threadIdx.x & 63;
    int wv = blockIdx.x * (blockDim.x >> 6) + (threadIdx.x >> 6);
    int nw = gridDim.x * (blockDim.x >> 6);
    float w[192];
#pragma unroll
    for (int k = 0; k < 64; k++) {
        w[k * 3 + 0] = whh_t[k * 192 + lane];
        w[k * 3 + 1] = whh_t[k * 192 + 64 + lane];
        w[k * 3 + 2] = whh_t[k * 192 + 128 + lane];
    }
    float b0 = bhh[lane], b1 = bhh[64 + lane], b2 = bhh[128 + lane];
    for (int n = wv; n < NN; n += nw) {
        float hreg = hin[n * 64 + lane];
        float a0 = b0, a1 = b1, a2 = b2;
#pragma unroll
        for (int k = 0; k < 64; k++) {
            float hv = lane_bcast(hreg, k);
            a0 = fmaf(hv, w[k * 3 + 0], a0);
            a1 = fmaf(hv, w[k * 3 + 1], a1);
            a2 = fmaf(hv, w[k * 3 + 2], a2);
        }
        float ir = gi[n * 192 + lane];
        float iz = gi[n * 192 + 64 + lane];
        float in_ = gi[n * 192 + 128 + lane];
        float r = 1.0f / (1.0f + expf(-(ir + a0)));
        float z = 1.0f / (1.0f + expf(-(iz + a1)));
        float nn = tanhf(in_ + r * a2);
        hout[n * 64 + lane] = (1.0f - z) * nn + z * hreg;
    }
}

// ---------------- launch ----------------

extern "C" void kernel_launch(void* const* d_in, const int* in_sizes, int n_in,
                              void* d_out, int out_size, void* d_ws, size_t ws_size,
                              hipStream_t stream) {
    const float* x   = (const float*)d_in[0];
    const int*   ei  = (const int*)d_in[1];
    const int*   src = ei;
    const int*   dst = ei + NE;
    const float* lw  = (const float*)d_in[2];
    const float* lb  = (const float*)d_in[3];
    const float* gw  = (const float*)d_in[4];
    const float* gb  = (const float*)d_in[5];
    const float* ggw = (const float*)d_in[6];
    const float* wih = (const float*)d_in[7];
    const float* whh = (const float*)d_in[8];
    const float* bih = (const float*)d_in[9];
    const float* bhh = (const float*)d_in[10];
    float* outp = (float*)d_out;

    char* ws = (char*)d_ws;
    size_t off = 0;
    auto take = [&](size_t bytes) -> char* {
        char* p = ws + off;
        off += (bytes + 255) & ~(size_t)255;
        return p;
    };
    int*   cnt    = (int*)take(NN * 4);
    int*   cur    = (int*)take(NN * 4);
    int*   rowptr = (int*)take((NN + 1) * 4);
    int*   bsum   = (int*)take((NB + 1) * 4);
    float* dinv   = (float*)take(NN * 4);
    int*   csrc   = (int*)take(NE * 4);
    float* cw     = (float*)take(NE * 4);
    float* lin_wt = (float*)take(8192 * 4);
    float* gcn_wt = (float*)take(122880 * 4);
    float* wih_t  = (float*)take(12288 * 4);
    float* whh_t  = (float*)take(12288 * 4);
    float* h      = (float*)take((size_t)NN * 64 * 4);
    float* t0     = (float*)take((size_t)NN * 64 * 4);
    float* t1     = (float*)take((size_t)NN * 64 * 4);
    float* gi     = (float*)take((size_t)NN * 192 * 4);
    (void)ws_size; (void)in_sizes; (void)n_in; (void)out_size;

    hipMemsetAsync(cnt, 0, NN * 4, stream);
    hipMemsetAsync(cur, 0, NN * 4, stream);

    hist_kernel<<<(NE + 255) / 256, 256, 0, stream>>>(dst, cnt);
    dinv_kernel<<<(NN + 255) / 256, 256, 0, stream>>>(cnt, dinv);
    scan1_kernel<<<NB, 256, 0, stream>>>(cnt, bsum);
    scan2_kernel<<<1, 64, 0, stream>>>(bsum);
    scan3_kernel<<<NB, 256, 0, stream>>>(cnt, bsum, rowptr);
    fill_kernel<<<(NE + 255) / 256, 256, 0, stream>>>(src, dst, dinv, rowptr, cur, csrc, cw);
    prep_weights<<<480, 256, 0, stream>>>(lw, gw, wih, whh, lin_wt, gcn_wt, wih_t, whh_t);

    init_linear<<<512, 256, 0, stream>>>(x, lin_wt, lb, h);

    for (int l = 0; l < N_GCN; l++) {
        mm64_kernel<<<1024, 256, 0, stream>>>(h, gcn_wt + l * 4096, t0);
        agg_kernel<true><<<(NN + 3) / 4, 256, 0, stream>>>(t0, rowptr, csrc, cw, dinv,
                                                           gb + l * 64, h);
    }

    for (int l = 0; l < N_GGC; l++) {
        mm64_kernel<<<1024, 256, 0, stream>>>(h, ggw + l * 4096, t0);
        agg_kernel<false><<<(NN + 3) / 4, 256, 0, stream>>>(t0, rowptr, csrc, nullptr, nullptr,
                                                            nullptr, t1);
        mm192_kernel<<<512, 256, 0, stream>>>(t1, wih_t, bih, gi);
        float* hdst = (l == N_GGC - 1) ? outp : h;
        gru_kernel<<<512, 256, 0, stream>>>(h, gi, whh_t, bhh, hdst);
    }
}

// Round 2
// 2552.005 us; speedup vs baseline: 1.6867x; 1.6867x over previous
//
#include <hip/hip_runtime.h>
#include <math.h>

#define NN 50000
#define NE 800000
#define DD 64
#define N_GCN 30
#define N_GGC 8
#define NB ((NN + 255) / 256)

__device__ __forceinline__ float lane_bcast(float v, int k) {
    return __int_as_float(__builtin_amdgcn_readlane(__float_as_int(v), k));
}

// ---------------- graph prep ----------------

__global__ void hist_kernel(const int* __restrict__ dst, int* __restrict__ cnt) {
    int i = blockIdx.x * blockDim.x + threadIdx.x;
    if (i < NE) atomicAdd(&cnt[dst[i]], 1);
}

__global__ void dinv_kernel(const int* __restrict__ cnt, float* __restrict__ dinv) {
    int i = blockIdx.x * blockDim.x + threadIdx.x;
    if (i < NN) dinv[i] = rsqrtf((float)cnt[i] + 1.0f);
}

__global__ void scan1_kernel(const int* __restrict__ cnt, int* __restrict__ bsum) {
    __shared__ int s[256];
    int tid = threadIdx.x;
    int i = blockIdx.x * 256 + tid;
    s[tid] = (i < NN) ? cnt[i] : 0;
    __syncthreads();
    for (int off = 128; off > 0; off >>= 1) {
        if (tid < off) s[tid] += s[tid + off];
        __syncthreads();
    }
    if (tid == 0) bsum[blockIdx.x] = s[0];
}

__global__ void scan2_kernel(int* __restrict__ bsum) {
    if (threadIdx.x == 0 && blockIdx.x == 0) {
        int acc = 0;
        for (int b = 0; b < NB; b++) { int v = bsum[b]; bsum[b] = acc; acc += v; }
        bsum[NB] = acc;
    }
}

__global__ void scan3_kernel(const int* __restrict__ cnt, const int* __restrict__ bsum,
                             int* __restrict__ rowptr) {
    __shared__ int s[256];
    int tid = threadIdx.x;
    int i = blockIdx.x * 256 + tid;
    int v = (i < NN) ? cnt[i] : 0;
    s[tid] = v;
    __syncthreads();
    for (int off = 1; off < 256; off <<= 1) {
        int t = (tid >= off) ? s[tid - off] : 0;
        __syncthreads();
        s[tid] += t;
        __syncthreads();
    }
    if (i < NN) rowptr[i] = bsum[blockIdx.x] + s[tid] - v;
    if (i == NN - 1) rowptr[NN] = bsum[blockIdx.x] + s[tid];
}

// packed edge record: .x = src node, .y = bitcast(norm weight)
__global__ void fill_kernel(const int* __restrict__ src, const int* __restrict__ dst,
                            const float* __restrict__ dinv, const int* __restrict__ rowptr,
                            int* __restrict__ cur, int2* __restrict__ epk) {
    int i = blockIdx.x * blockDim.x + threadIdx.x;
    if (i >= NE) return;
    int s = src[i], d = dst[i];
    int pos = atomicAdd(&cur[d], 1);
    int idx = rowptr[d] + pos;
    float w = dinv[s] * dinv[d];
    epk[idx] = make_int2(s, __float_as_int(w));
}

// ---------------- weight prep (transposes) ----------------

__global__ void prep_weights(const float* __restrict__ lw, const float* __restrict__ gw,
                             const float* __restrict__ wih, const float* __restrict__ whh,
                             float* __restrict__ lin_wt, float* __restrict__ gcn_wt,
                             float* __restrict__ wih_t, float* __restrict__ whh_t) {
    int i = blockIdx.x * blockDim.x + threadIdx.x;
    if (i < 8192) {              // lin_wt[k*64+j] = lw[j*128+k], k<128, j<64
        int k = i >> 6, j = i & 63;
        lin_wt[k * 64 + j] = lw[j * 128 + k];
    }
    if (i < 122880) {            // gcn_wt[l][k][j] = gw[l][j][k]
        int l = i >> 12, r = i & 4095;
        int k = r >> 6, j = r & 63;
        gcn_wt[l * 4096 + k * 64 + j] = gw[l * 4096 + j * 64 + k];
    }
    if (i < 12288) {             // i = j*64+k, j<192, k<64
        int j = i >> 6, k = i & 63;
        wih_t[k * 192 + j] = wih[i];
        whh_t[k * 192 + j] = whh[i];
    }
}

// ---------------- init linear: h = relu(x @ lw^T + lb), K=128 ----------------

__global__ __launch_bounds__(256) void init_linear(const float* __restrict__ x,
                                                   const float* __restrict__ lin_wt,
                                                   const float* __restrict__ lb,
                                                   float* __restrict__ h) {
    int lane = threadIdx.x & 63;
    int wv = blockIdx.x * (blockDim.x >> 6) + (threadIdx.x >> 6);
    int nw = gridDim.x * (blockDim.x >> 6);
    float w[128];
#pragma unroll
    for (int k = 0; k < 128; k++) w[k] = lin_wt[k * 64 + lane];
    float b = lb[lane];
    for (int n = wv; n < NN; n += nw) {
        float x0 = x[n * 128 + lane];
        float x1 = x[n * 128 + 64 + lane];
        float a0 = b, a1 = 0.f, a2 = 0.f, a3 = 0.f;
#pragma unroll
        for (int k = 0; k < 64; k += 4) {
            a0 = fmaf(lane_bcast(x0, k), w[k], a0);
            a1 = fmaf(lane_bcast(x0, k + 1), w[k + 1], a1);
            a2 = fmaf(lane_bcast(x0, k + 2), w[k + 2], a2);
            a3 = fmaf(lane_bcast(x0, k + 3), w[k + 3], a3);
        }
#pragma unroll
        for (int k = 0; k < 64; k += 4) {
            a0 = fmaf(lane_bcast(x1, k), w[64 + k], a0);
            a1 = fmaf(lane_bcast(x1, k + 1), w[64 + k + 1], a1);
            a2 = fmaf(lane_bcast(x1, k + 2), w[64 + k + 2], a2);
            a3 = fmaf(lane_bcast(x1, k + 3), w[64 + k + 3], a3);
        }
        h[n * 64 + lane] = fmaxf((a0 + a1) + (a2 + a3), 0.0f);
    }
}

// ---------------- mm64: out[n][j] = sum_k in[n][k] * wt[k][j] ----------------

__global__ __launch_bounds__(256) void mm64_kernel(const float* __restrict__ in,
                                                   const float* __restrict__ wt,
                                                   float* __restrict__ out) {
    int lane = threadIdx.x & 63;
    int wv = blockIdx.x * (blockDim.x >> 6) + (threadIdx.x >> 6);
    int nw = gridDim.x * (blockDim.x >> 6);
    float w[64];
#pragma unroll
    for (int k = 0; k < 64; k++) w[k] = wt[k * 64 + lane];
    for (int n = wv; n < NN; n += nw) {
        float hreg = in[n * 64 + lane];
        float a0 = 0.f, a1 = 0.f, a2 = 0.f, a3 = 0.f;
#pragma unroll
        for (int k = 0; k < 64; k += 4) {
            a0 = fmaf(lane_bcast(hreg, k), w[k], a0);
            a1 = fmaf(lane_bcast(hreg, k + 1), w[k + 1], a1);
            a2 = fmaf(lane_bcast(hreg, k + 2), w[k + 2], a2);
            a3 = fmaf(lane_bcast(hreg, k + 3), w[k + 3], a3);
        }
        out[n * 64 + lane] = (a0 + a1) + (a2 + a3);
    }
}

// ---------------- mm192: out[n][g*64+j] = bias + sum_k in[n][k] * wt[k][g*64+j] ----

__global__ __launch_bounds__(256, 2) void mm192_kernel(const float* __restrict__ in,
                                                       const float* __restrict__ wt,
                                                       const float* __restrict__ bias,
                                                       float* __restrict__ out) {
    int lane = threadIdx.x & 63;
    int wv = blockIdx.x * (blockDim.x >> 6) + (threadIdx.x >> 6);
    int nw = gridDim.x * (blockDim.x >> 6);
    float w[192];
#pragma unroll
    for (int k = 0; k < 64; k++) {
        w[k * 3 + 0] = wt[k * 192 + lane];
        w[k * 3 + 1] = wt[k * 192 + 64 + lane];
        w[k * 3 + 2] = wt[k * 192 + 128 + lane];
    }
    float b0 = bias[lane], b1 = bias[64 + lane], b2 = bias[128 + lane];
    for (int n = wv; n < NN; n += nw) {
        float hreg = in[n * 64 + lane];
        float a0 = b0, a1 = b1, a2 = b2;
#pragma unroll
        for (int k = 0; k < 64; k++) {
            float hv = lane_bcast(hreg, k);
            a0 = fmaf(hv, w[k * 3 + 0], a0);
            a1 = fmaf(hv, w[k * 3 + 1], a1);
            a2 = fmaf(hv, w[k * 3 + 2], a2);
        }
        out[n * 192 + lane] = a0;
        out[n * 192 + 64 + lane] = a1;
        out[n * 192 + 128 + lane] = a2;
    }
}

// ---------------- aggregation: wave per node, 4 edges/iter, float4 lanes ------
// lane = sub*16 + q : sub = edge slot (0..3), q = dim quarter (dims q*4..q*4+3)

template <bool NORM>
__global__ __launch_bounds__(256) void agg_kernel(const float* __restrict__ xw,
                                                  const int* __restrict__ rowptr,
                                                  const int2* __restrict__ epk,
                                                  const float* __restrict__ dinv,
                                                  const float* __restrict__ bias,
                                                  float* __restrict__ out) {
    int lane = threadIdx.x & 63;
    int sub = lane >> 4;
    int q = lane & 15;
    int wv = blockIdx.x * (blockDim.x >> 6) + (threadIdx.x >> 6);
    int nw = gridDim.x * (blockDim.x >> 6);

    float4 b4 = make_float4(0.f, 0.f, 0.f, 0.f);
    if (NORM) b4 = *(const float4*)&bias[q * 4];

    for (int n = wv; n < NN; n += nw) {
        int e0 = rowptr[n], e1 = rowptr[n + 1];
        float ax = 0.f, ay = 0.f, az = 0.f, aw = 0.f;

        int e = e0 + sub;
        // unrolled by 2: 8 edges in flight per wave
        while (e + 4 < e1) {
            int2 p0 = epk[e];
            int2 p1 = epk[e + 4];
            float4 v0 = *(const float4*)&xw[(size_t)p0.x * 64 + q * 4];
            float4 v1 = *(const float4*)&xw[(size_t)p1.x * 64 + q * 4];
            float w0 = NORM ? __int_as_float(p0.y) : 1.0f;
            float w1 = NORM ? __int_as_float(p1.y) : 1.0f;
            ax = fmaf(w0, v0.x, ax); ay = fmaf(w0, v0.y, ay);
            az = fmaf(w0, v0.z, az); aw = fmaf(w0, v0.w, aw);
            ax = fmaf(w1, v1.x, ax); ay = fmaf(w1, v1.y, ay);
            az = fmaf(w1, v1.z, az); aw = fmaf(w1, v1.w, aw);
            e += 8;
        }
        if (e < e1) {
            int2 p0 = epk[e];
            float4 v0 = *(const float4*)&xw[(size_t)p0.x * 64 + q * 4];
            float w0 = NORM ? __int_as_float(p0.y) : 1.0f;
            ax = fmaf(w0, v0.x, ax); ay = fmaf(w0, v0.y, ay);
            az = fmaf(w0, v0.z, az); aw = fmaf(w0, v0.w, aw);
        }

        // reduce the 4 edge slots (lanes differing in bits 4,5)
        ax += __shfl_xor(ax, 16); ay += __shfl_xor(ay, 16);
        az += __shfl_xor(az, 16); aw += __shfl_xor(aw, 16);
        ax += __shfl_xor(ax, 32); ay += __shfl_xor(ay, 32);
        az += __shfl_xor(az, 32); aw += __shfl_xor(aw, 32);

        if (sub == 0) {
            float4 r;
            if (NORM) {
                float di = dinv[n];
                float dd = di * di;
                float4 sv = *(const float4*)&xw[(size_t)n * 64 + q * 4];
                r.x = ax + b4.x + dd * sv.x;
                r.y = ay + b4.y + dd * sv.y;
                r.z = az + b4.z + dd * sv.z;
                r.w = aw + b4.w + dd * sv.w;
            } else {
                r.x = ax; r.y = ay; r.z = az; r.w = aw;
            }
            *(float4*)&out[(size_t)n * 64 + q * 4] = r;
        }
    }
}

// ---------------- fused GRU: h' = (1-z)*n + z*h ----------------

__global__ __launch_bounds__(256, 2) void gru_kernel(const float* __restrict__ hin,
                                                     const float* __restrict__ gi,
                                                     const float* __restrict__ whh_t,
                                                     const float* __restrict__ bhh,
                                                     float* __restrict__ hout) {
    int lane = threadIdx.x & 63;
    int wv = blockIdx.x * (blockDim.x >> 6) + (threadIdx.x >> 6);
    int nw = gridDim.x * (blockDim.x >> 6);
    float w[192];
#pragma unroll
    for (int k = 0; k < 64; k++) {
        w[k * 3 + 0] = whh_t[k * 192 + lane];
        w[k * 3 + 1] = whh_t[k * 192 + 64 + lane];
        w[k * 3 + 2] = whh_t[k * 192 + 128 + lane];
    }
    float b0 = bhh[lane], b1 = bhh[64 + lane], b2 = bhh[128 + lane];
    for (int n = wv; n < NN; n += nw) {
        float hreg = hin[n * 64 + lane];
        float a0 = b0, a1 = b1, a2 = b2;
#pragma unroll
        for (int k = 0; k < 64; k++) {
            float hv = lane_bcast(hreg, k);
            a0 = fmaf(hv, w[k * 3 + 0], a0);
            a1 = fmaf(hv, w[k * 3 + 1], a1);
            a2 = fmaf(hv, w[k * 3 + 2], a2);
        }
        float ir = gi[n * 192 + lane];
        float iz = gi[n * 192 + 64 + lane];
        float in_ = gi[n * 192 + 128 + lane];
        float r = 1.0f / (1.0f + expf(-(ir + a0)));
        float z = 1.0f / (1.0f + expf(-(iz + a1)));
        float nn = tanhf(in_ + r * a2);
        hout[n * 64 + lane] = (1.0f - z) * nn + z * hreg;
    }
}

// ---------------- launch ----------------

extern "C" void kernel_launch(void* const* d_in, const int* in_sizes, int n_in,
                              void* d_out, int out_size, void* d_ws, size_t ws_size,
                              hipStream_t stream) {
    const float* x   = (const float*)d_in[0];
    const int*   ei  = (const int*)d_in[1];
    const int*   src = ei;
    const int*   dst = ei + NE;
    const float* lw  = (const float*)d_in[2];
    const float* lb  = (const float*)d_in[3];
    const float* gw  = (const float*)d_in[4];
    const float* gb  = (const float*)d_in[5];
    const float* ggw = (const float*)d_in[6];
    const float* wih = (const float*)d_in[7];
    const float* whh = (const float*)d_in[8];
    const float* bih = (const float*)d_in[9];
    const float* bhh = (const float*)d_in[10];
    float* outp = (float*)d_out;

    char* ws = (char*)d_ws;
    size_t off = 0;
    auto take = [&](size_t bytes) -> char* {
        char* p = ws + off;
        off += (bytes + 255) & ~(size_t)255;
        return p;
    };
    int*   cnt    = (int*)take(NN * 4);
    int*   cur    = (int*)take(NN * 4);
    int*   rowptr = (int*)take((NN + 1) * 4);
    int*   bsum   = (int*)take((NB + 1) * 4);
    float* dinv   = (float*)take(NN * 4);
    int2*  epk    = (int2*)take((size_t)NE * 8);
    float* lin_wt = (float*)take(8192 * 4);
    float* gcn_wt = (float*)take(122880 * 4);
    float* wih_t  = (float*)take(12288 * 4);
    float* whh_t  = (float*)take(12288 * 4);
    float* h      = (float*)take((size_t)NN * 64 * 4);
    float* t0     = (float*)take((size_t)NN * 64 * 4);
    float* t1     = (float*)take((size_t)NN * 64 * 4);
    float* gi     = (float*)take((size_t)NN * 192 * 4);
    (void)ws_size; (void)in_sizes; (void)n_in; (void)out_size;

    hipMemsetAsync(cnt, 0, NN * 4, stream);
    hipMemsetAsync(cur, 0, NN * 4, stream);

    hist_kernel<<<(NE + 255) / 256, 256, 0, stream>>>(dst, cnt);
    dinv_kernel<<<(NN + 255) / 256, 256, 0, stream>>>(cnt, dinv);
    scan1_kernel<<<NB, 256, 0, stream>>>(cnt, bsum);
    scan2_kernel<<<1, 64, 0, stream>>>(bsum);
    scan3_kernel<<<NB, 256, 0, stream>>>(cnt, bsum, rowptr);
    fill_kernel<<<(NE + 255) / 256, 256, 0, stream>>>(src, dst, dinv, rowptr, cur, epk);
    prep_weights<<<480, 256, 0, stream>>>(lw, gw, wih, whh, lin_wt, gcn_wt, wih_t, whh_t);

    init_linear<<<512, 256, 0, stream>>>(x, lin_wt, lb, h);

    for (int l = 0; l < N_GCN; l++) {
        mm64_kernel<<<1024, 256, 0, stream>>>(h, gcn_wt + l * 4096, t0);
        agg_kernel<true><<<(NN + 3) / 4, 256, 0, stream>>>(t0, rowptr, epk, dinv,
                                                           gb + l * 64, h);
    }

    for (int l = 0; l < N_GGC; l++) {
        mm64_kernel<<<1024, 256, 0, stream>>>(h, ggw + l * 4096, t0);
        agg_kernel<false><<<(NN + 3) / 4, 256, 0, stream>>>(t0, rowptr, epk, nullptr,
                                                            nullptr, t1);
        mm192_kernel<<<512, 256, 0, stream>>>(t1, wih_t, bih, gi);
        float* hdst = (l == N_GGC - 1) ? outp : h;
        gru_kernel<<<512, 256, 0, stream>>>(h, gi, whh_t, bhh, hdst);
    }
}